// Round 3
// baseline (331.522 us; speedup 1.0000x reference)
//
#include <hip/hip_runtime.h>
#include <hip/hip_bf16.h>
#include <stdint.h>

#define N 4096
// gemm_sym 8-phase geometry (256^2 triangular, fp8, BK=128):
#define SM 256
#define SK 128
// gemm_pv 8-phase geometry:
#define PM 256
#define PN 256
#define PK 64

typedef __hip_bfloat16 bf16;
typedef __attribute__((ext_vector_type(8))) __bf16 bfrag;   // 8 bf16 (MFMA A/B operand)
typedef __attribute__((ext_vector_type(4))) float floatx4;  // MFMA C/D operand
typedef __attribute__((ext_vector_type(8))) int i32x8;      // 32 fp8 (f8f6f4 A/B operand)
typedef __attribute__((ext_vector_type(4))) int i32x4;

// ---------------------------------------------------------------------------
// async global -> LDS, 16B per lane (global_load_lds_dwordx4)
// ---------------------------------------------------------------------------
__device__ __forceinline__ void gld_lds16(const void* g, void* l) {
    __builtin_amdgcn_global_load_lds(
        (const __attribute__((address_space(1))) void*)g,
        (__attribute__((address_space(3))) void*)l, 16, 0, 0);
}

__device__ __forceinline__ unsigned short f2bf(float x) {
    __hip_bfloat16 h = __float2bfloat16(x);
    return *(unsigned short*)&h;
}

#define PV_BAR()   __builtin_amdgcn_s_barrier()
#define PV_LGKM0() asm volatile("s_waitcnt lgkmcnt(0)" ::: "memory")
#define PV_VM4()   asm volatile("s_waitcnt vmcnt(4)" ::: "memory")

// ---------------------------------------------------------------------------
// Kernel 1: xb = bf16(in * 1/64)  (scaled, for gemm_pv's B operand)
//           x8 = fp8_e4m3(in)     (UNSCALED -- full e4m3 relative precision;
//                                  the 1/4096 is applied exactly via the MFMA
//                                  e8m0 scale operands, 2^-6 per operand)
// blocks 0..15 also zero rowsum (replaces the memset dispatch).
// ---------------------------------------------------------------------------
__global__ __launch_bounds__(256) void cvt_scale(const float* __restrict__ in,
                                                 unsigned short* __restrict__ xb,
                                                 uint8_t* __restrict__ x8,
                                                 float* __restrict__ rowsum) {
    if (blockIdx.x < 16) rowsum[blockIdx.x * 256 + threadIdx.x] = 0.f;
    const long i = ((long)blockIdx.x * 256 + threadIdx.x) * 8;
    float4 a = *(const float4*)(in + i);
    float4 b = *(const float4*)(in + i + 4);
    const float sc = 0.015625f;  // 1/64 = 1/sqrt(4096)
    float v[8] = {a.x, a.y, a.z, a.w, b.x, b.y, b.z, b.w};
    alignas(16) unsigned short r[8];
#pragma unroll
    for (int k = 0; k < 8; ++k) r[k] = f2bf(v[k] * sc);
    *(uint4*)(xb + i) = *(const uint4*)r;

    int p0 = __builtin_amdgcn_cvt_pk_fp8_f32(v[0], v[1], 0, false);
    p0     = __builtin_amdgcn_cvt_pk_fp8_f32(v[2], v[3], p0, true);
    int p1 = __builtin_amdgcn_cvt_pk_fp8_f32(v[4], v[5], 0, false);
    p1     = __builtin_amdgcn_cvt_pk_fp8_f32(v[6], v[7], p1, true);
    int2 pk; pk.x = p0; pk.y = p1;
    *(int2*)(x8 + i) = pk;
}

// ---------------------------------------------------------------------------
// Kernel 2 (gemm_sym): E = exp(mask(x x^T)), triangular 136-block grid of
// 256^2 tiles, 512 threads (8 waves, 2Mx4N, 128x64 per-wave tile).
// R7/R8: gemm_pv 8-phase skeleton (T3+T4 counted vmcnt + T5 setprio) with
// BK=128 fp8, LDS = 2buf x (A 256x128 + B 256x128) = 128 KiB, 8 x
// mfma_scale_f32_16x16x128_f8f6f4 per phase (e8m0 scales 2^-6 -> exact
// 1/4096).  R8 FIX: B-fragments must be double-banked by nj (bfr[nj][j])
// exactly like pv's br[nj][g][k] -- R7's single bfr[2] was clobbered by
// ph2/ph6's LDB(nj=1), so ph4/ph8's MM(mi1,nj0) multiplied the wrong B
// (quadrant (1,0) duplicated (1,1)).  A-fragments (af) are reloaded every
// two phases BEFORE use, so single-banked af[4] is correct.
// Stage/read/wait placement identical to pv:
//   buf0.A read ph1,3  staged ph5,6   | buf0.B read ph1,2  staged ph3,4
//   buf1.A read ph5,7  staged ph1,2   | buf1.B read ph5,6  staged ph7,8
//   vmcnt(4) only at ph4/ph8 ends.
// LDS swizzle: slot b of a 128B row holds global 16B k-block b^(row&7)
// (source-side XOR, 0-conflict R2-R6); fragment read slots (2q)^l7,
// (2q+1)^l7.  All 136 blocks have identical K-work, 1 block/CU.
// ---------------------------------------------------------------------------
#define SY_STAGE_A(buf, h, k0) do { \
    const uint8_t* s_ = Asrc + (h) * 128 * (long)N + (k0); \
    uint8_t* d_ = dstl + (buf) * 32768 + (h) * 16384; \
    gld_lds16(s_, d_); \
    gld_lds16(s_ + 64 * (long)N, d_ + 8192); } while (0)

#define SY_STAGE_B(buf, h, k0) do { \
    const uint8_t* s_ = Bsrc + (h) * 128 * (long)N + (k0); \
    uint8_t* d_ = dstl + 65536 + (buf) * 32768 + (h) * 16384; \
    gld_lds16(s_, d_); \
    gld_lds16(s_ + 64 * (long)N, d_ + 8192); } while (0)

#define SY_LDA(buf, mi) do { \
    const uint8_t* b_ = smem + (buf) * 32768; \
    _Pragma("unroll") for (int i_ = 0; i_ < 4; ++i_) { \
      const int r_ = wm * 128 + (mi) * 64 + i_ * 16 + l15; \
      i32x4 lo_ = *(const i32x4*)&b_[(r_ * 8 + ((2 * q) ^ l7)) * 16]; \
      i32x4 hi_ = *(const i32x4*)&b_[(r_ * 8 + ((2 * q + 1) ^ l7)) * 16]; \
      af[i_] = (i32x8){lo_.x, lo_.y, lo_.z, lo_.w, hi_.x, hi_.y, hi_.z, hi_.w}; } } while (0)

#define SY_LDB(buf, nj) do { \
    const uint8_t* b_ = smem + 65536 + (buf) * 32768; \
    _Pragma("unroll") for (int j_ = 0; j_ < 2; ++j_) { \
      const int r_ = wn * 64 + (nj) * 32 + j_ * 16 + l15; \
      i32x4 lo_ = *(const i32x4*)&b_[(r_ * 8 + ((2 * q) ^ l7)) * 16]; \
      i32x4 hi_ = *(const i32x4*)&b_[(r_ * 8 + ((2 * q + 1) ^ l7)) * 16]; \
      bfr[nj][j_] = (i32x8){lo_.x, lo_.y, lo_.z, lo_.w, hi_.x, hi_.y, hi_.z, hi_.w}; } } while (0)

#define SY_MM(mi, nj) do { \
    __builtin_amdgcn_s_setprio(1); \
    _Pragma("unroll") for (int i_ = 0; i_ < 4; ++i_) \
    _Pragma("unroll") for (int j_ = 0; j_ < 2; ++j_) \
      acc[(mi)*4+i_][(nj)*2+j_] = __builtin_amdgcn_mfma_scale_f32_16x16x128_f8f6f4( \
          af[i_], bfr[nj][j_], acc[(mi)*4+i_][(nj)*2+j_], \
          0, 0, 0, 0x79797979, 0, 0x79797979); \
    __builtin_amdgcn_s_setprio(0); } while (0)

__global__ __launch_bounds__(512, 2) void gemm_sym(const uint8_t* __restrict__ X8,
                                                   unsigned short* __restrict__ E,
                                                   float* __restrict__ rowsum) {
    __shared__ __align__(16) uint8_t smem[131072];  // A0 A1 | B0 B1 (32KB each)

    const int t    = threadIdx.x;
    const int lane = t & 63;
    const int wm   = (t >> 6) >> 2;  // 0..1 (128-row strip)
    const int wn   = (t >> 6) & 3;   // 0..3 (64-col strip)
    const int l15  = lane & 15;
    const int l7   = lane & 7;
    const int q    = lane >> 4;

    // decode triangular block index: b = I*(I+1)/2 + J, J <= I  (16 rows)
    const int b = blockIdx.x;
    int I = (int)((sqrtf((float)(8 * b + 1)) - 1.0f) * 0.5f);
    if ((I + 1) * (I + 2) / 2 <= b) ++I;   // fp-safety fixups
    if (I * (I + 1) / 2 > b) --I;
    const int Jb = b - I * (I + 1) / 2;
    const int bm = I * SM;   // row block (>= col block)
    const int bn = Jb * SM;
    const bool diag = (I == Jb);

    // staging: slot s=t covers row srow (64 rows/issue), 16B-block t&7
    // holding global k-block (t&7)^(srow&7)  [source-side XOR swizzle]
    const int srow = t >> 3;
    const int skb  = (t & 7) ^ (srow & 7);
    const uint8_t* Asrc = X8 + (long)(bm + srow) * N + skb * 16;
    const uint8_t* Bsrc = X8 + (long)(bn + srow) * N + skb * 16;
    uint8_t* dstl = smem + t * 16;

    floatx4 acc[8][4] = {};
    i32x8 af[4], bfr[2][2];

    // prologue: B(0),A(0) -> buf0; B(1) -> buf1.  A(1) staged in ph1/2.
    SY_STAGE_B(0, 0, 0); SY_STAGE_B(0, 1, 0);
    SY_STAGE_A(0, 0, 0); SY_STAGE_A(0, 1, 0);
    SY_STAGE_B(1, 0, SK); SY_STAGE_B(1, 1, SK);
    PV_VM4();  // B(0)+A(0) landed; B(1)'s 4 loads stay in flight
    PV_BAR();

    for (int i = 0; i < 16; ++i) {
        const int ka1 = ((2 * i + 1) * SK) & (N - 1);
        const int kb2 = ((2 * i + 2) * SK) & (N - 1);  // also A(2i+2) offset
        const int kb3 = ((2 * i + 3) * SK) & (N - 1);
        // ph1: K-tile 2i, quadrant (mi0,nj0)     [12 ds_read_b128]
        SY_LDA(0, 0); SY_LDB(0, 0); SY_STAGE_A(1, 0, ka1);
        PV_BAR(); PV_LGKM0();
        SY_MM(0, 0);
        PV_BAR();
        // ph2: (mi0,nj1)                          [4 ds_read]
        SY_LDB(0, 1); SY_STAGE_A(1, 1, ka1);
        PV_BAR(); PV_LGKM0();
        SY_MM(0, 1);
        PV_BAR();
        // ph3: (mi1,nj1)                          [8 ds_read]
        SY_LDA(0, 1); SY_STAGE_B(0, 0, kb2);
        PV_BAR(); PV_LGKM0();
        SY_MM(1, 1);
        PV_BAR();
        // ph4: (mi1,nj0) -- regs only (bfr[0] from ph1); wait A(2i+1)
        SY_STAGE_B(0, 1, kb2);
        PV_BAR();
        SY_MM(1, 0);
        PV_VM4(); PV_BAR();
        // ph5: K-tile 2i+1, (mi0,nj0)
        SY_LDA(1, 0); SY_LDB(1, 0); SY_STAGE_A(0, 0, kb2);
        PV_BAR(); PV_LGKM0();
        SY_MM(0, 0);
        PV_BAR();
        // ph6: (mi0,nj1)
        SY_LDB(1, 1); SY_STAGE_A(0, 1, kb2);
        PV_BAR(); PV_LGKM0();
        SY_MM(0, 1);
        PV_BAR();
        // ph7: (mi1,nj1)
        SY_LDA(1, 1); SY_STAGE_B(1, 0, kb3);
        PV_BAR(); PV_LGKM0();
        SY_MM(1, 1);
        PV_BAR();
        // ph8: (mi1,nj0) -- regs only (bfr[0] from ph5); wait tile 2i+2
        SY_STAGE_B(1, 1, kb3);
        PV_BAR();
        SY_MM(1, 0);
        PV_VM4(); PV_BAR();
    }

    // ---- epilogue: C/D layout col=lane&15, row=(lane>>4)*4+reg ----
    const int col0 = bn + wn * 64 + l15;
    const int row0 = bm + wm * 128 + q * 4;

#pragma unroll
    for (int f = 0; f < 8; ++f) {
#pragma unroll
        for (int r = 0; r < 4; ++r) {
            const int row = row0 + f * 16 + r;
            float rs = 0.f;
#pragma unroll
            for (int g = 0; g < 4; ++g) {
                const int col = col0 + g * 16;
                // no max-subtraction: sims ~ +-0.3, exp safe; shift cancels.
                float e = (row == col) ? 0.f : __expf(acc[f][g][r]);
                acc[f][g][r] = e;
                rs += e;
                E[(long)row * N + col] = f2bf(e);
            }
#pragma unroll
            for (int off = 1; off < 16; off <<= 1) rs += __shfl_xor(rs, off);
            if (l15 == 0) atomicAdd(rowsum + row, rs);
        }
    }

    if (!diag) {
        // column sums -> row sums of the mirror tile
#pragma unroll
        for (int g = 0; g < 4; ++g) {
            float cs = 0.f;
#pragma unroll
            for (int f = 0; f < 8; ++f)
#pragma unroll
                for (int r = 0; r < 4; ++r) cs += acc[f][g][r];
            cs += __shfl_xor(cs, 16);
            cs += __shfl_xor(cs, 32);
            if (q == 0) atomicAdd(rowsum + bn + wn * 64 + g * 16 + l15, cs);
        }

        // per-wave 128x64 -> 64x128 transpose through swizzled LDS
        // (16 KB/wave, aliases the staging buffers; __syncthreads drains
        // each wave's surplus prefetch vmcnt before any tb write)
        unsigned short* tb = (unsigned short*)smem + (t >> 6) * 8192;
        __syncthreads();
#pragma unroll
        for (int f = 0; f < 8; ++f) {
            const int lr0 = f * 16 + q * 4;        // row-in-wave-tile, 4-run
            const int blk = lr0 >> 3;              // 16B block 0..15
            const int half = (lr0 >> 2) & 1;
#pragma unroll
            for (int g = 0; g < 4; ++g) {
                const int lc = g * 16 + l15;       // col-in-wave-tile 0..63
                union { unsigned short u[4]; uint2 v2; } pk;
#pragma unroll
                for (int r = 0; r < 4; ++r) pk.u[r] = f2bf(acc[f][g][r]);
                *(uint2*)&tb[lc * 128 + 8 * (blk ^ (lc & 15)) + 4 * half] = pk.v2;
            }
        }
        __syncthreads();

#pragma unroll
        for (int p = 0; p < 16; ++p) {
            const int gr = p * 4 + q;              // mirror row 0..63
            const int cb = l15;                    // 8-elem chunk 0..15
            uint4 v = *(const uint4*)&tb[gr * 128 + 8 * (cb ^ (gr & 15))];
            *(uint4*)&E[(long)(bn + wn * 64 + gr) * N + bm + wm * 128 + cb * 8] = v;
        }
    }
}

// ---------------------------------------------------------------------------
// Kernel 3 (gemm_pv): out = (E/rowsum) x^T.  256^2 8-phase schedule
// (T3+T4 counted-vmcnt + T5 setprio) -- unchanged from R6 (verified,
// 118 us / 1160 TF / MfmaUtil 49.5%).
// ---------------------------------------------------------------------------
#define PV_STAGE_A(buf, h, k0) do { \
    const bf16* s_ = Asrc + (h) * 128 * (long)N + (k0); \
    bf16* d_ = dstl + (buf) * 16384 + (h) * 8192; \
    gld_lds16(s_, d_); \
    gld_lds16(s_ + 64 * (long)N, d_ + 4096); } while (0)

#define PV_STAGE_B(buf, h, k0) do { \
    const bf16* s_ = Bsrc + (h) * 128 * (long)N + (k0); \
    bf16* d_ = dstl + 32768 + (buf) * 16384 + (h) * 8192; \
    gld_lds16(s_, d_); \
    gld_lds16(s_ + 64 * (long)N, d_ + 4096); } while (0)

#define PV_LDA(buf, mi) do { \
    const bf16* b_ = lds + (buf) * 16384; \
    _Pragma("unroll") for (int f_ = 0; f_ < 4; ++f_) { \
      const int r_ = wm * 128 + (mi) * 64 + f_ * 16 + l15; \
      ar[f_][0] = *(const bfrag*)&b_[(r_ * 8 + (q ^ l7)) * 8]; \
      ar[f_][1] = *(const bfrag*)&b_[(r_ * 8 + ((4 + q) ^ l7)) * 8]; } } while (0)

#define PV_LDB(buf, nj) do { \
    const bf16* b_ = lds + 32768 + (buf) * 16384; \
    _Pragma("unroll") for (int g_ = 0; g_ < 2; ++g_) { \
      const int r_ = wn * 64 + (nj) * 32 + g_ * 16 + l15; \
      br[nj][g_][0] = *(const bfrag*)&b_[(r_ * 8 + (q ^ l7)) * 8]; \
      br[nj][g_][1] = *(const bfrag*)&b_[(r_ * 8 + ((4 + q) ^ l7)) * 8]; } } while (0)

#define PV_MM(mi, nj) do { \
    __builtin_amdgcn_s_setprio(1); \
    _Pragma("unroll") for (int f_ = 0; f_ < 4; ++f_) \
    _Pragma("unroll") for (int g_ = 0; g_ < 2; ++g_) \
    _Pragma("unroll") for (int k_ = 0; k_ < 2; ++k_) \
      acc[(mi)*4+f_][(nj)*2+g_] = __builtin_amdgcn_mfma_f32_16x16x32_bf16( \
          ar[f_][k_], br[nj][g_][k_], acc[(mi)*4+f_][(nj)*2+g_], 0, 0, 0); \
    __builtin_amdgcn_s_setprio(0); } while (0)

__global__ __launch_bounds__(512, 2) void gemm_pv(const bf16* __restrict__ A,
                                                  const bf16* __restrict__ B,
                                                  float* __restrict__ C,
                                                  const float* __restrict__ rowsum) {
    __shared__ __align__(16) bf16 lds[4 * 16384];  // 128 KiB: A0 A1 B0 B1

    const int t    = threadIdx.x;
    const int lane = t & 63;
    const int wm   = (t >> 6) >> 2;  // 0..1 (128-row strip)
    const int wn   = (t >> 6) & 3;   // 0..3 (64-col strip)
    const int l15  = lane & 15;
    const int l7   = lane & 7;
    const int q    = lane >> 4;

    // bijective XCD swizzle (256 blocks % 8 XCDs == 0)
    const int swz = (blockIdx.x & 7) * 32 + (blockIdx.x >> 3);
    const int bm  = (swz >> 4) * PM;
    const int bn  = (swz & 15) * PN;

    const int srow = t >> 3;
    const int skb  = (t & 7) ^ (srow & 7);
    const bf16* Asrc = A + (long)(bm + srow) * N + skb * 8;
    const bf16* Bsrc = B + (long)(bn + srow) * N + skb * 8;
    bf16* dstl = lds + t * 8;

    floatx4 acc[8][4] = {};
    bfrag ar[4][2], br[2][2][2];

    // prologue: B(0),A(0) -> buf0; B(1) -> buf1.  A(1) staged in ph1/2.
    PV_STAGE_B(0, 0, 0); PV_STAGE_B(0, 1, 0);
    PV_STAGE_A(0, 0, 0); PV_STAGE_A(0, 1, 0);
    PV_STAGE_B(1, 0, PK); PV_STAGE_B(1, 1, PK);
    PV_VM4();
    PV_BAR();

    for (int i = 0; i < 32; ++i) {
        const int ka1 = ((2 * i + 1) * PK) & (N - 1);
        const int kb2 = ((2 * i + 2) * PK) & (N - 1);
        const int kb3 = ((2 * i + 3) * PK) & (N - 1);
        PV_LDA(0, 0); PV_LDB(0, 0); PV_STAGE_A(1, 0, ka1);
        PV_BAR(); PV_LGKM0();
        PV_MM(0, 0);
        PV_BAR();
        PV_LDB(0, 1); PV_STAGE_A(1, 1, ka1);
        PV_BAR(); PV_LGKM0();
        PV_MM(0, 1);
        PV_BAR();
        PV_LDA(0, 1); PV_STAGE_B(0, 0, kb2);
        PV_BAR(); PV_LGKM0();
        PV_MM(1, 1);
        PV_BAR();
        PV_STAGE_B(0, 1, kb2);
        PV_BAR();
        PV_MM(1, 0);
        PV_VM4(); PV_BAR();
        PV_LDA(1, 0); PV_LDB(1, 0); PV_STAGE_A(0, 0, kb2);
        PV_BAR(); PV_LGKM0();
        PV_MM(0, 0);
        PV_BAR();
        PV_LDB(1, 1); PV_STAGE_A(0, 1, kb2);
        PV_BAR(); PV_LGKM0();
        PV_MM(0, 1);
        PV_BAR();
        PV_LDA(1, 1); PV_STAGE_B(1, 0, kb3);
        PV_BAR(); PV_LGKM0();
        PV_MM(1, 1);
        PV_BAR();
        PV_STAGE_B(1, 1, kb3);
        PV_BAR();
        PV_MM(1, 0);
        PV_VM4(); PV_BAR();
    }

    // epilogue: C/D layout col=lane&15, row=q*4+reg; fuse 1/rowsum
    const int rowbase = bm + wm * 128 + q * 4;
    const int colbase = bn + wn * 64 + l15;
#pragma unroll
    for (int f = 0; f < 8; ++f) {
#pragma unroll
        for (int r = 0; r < 4; ++r) {
            const int row = rowbase + f * 16 + r;
            const float inv = 1.0f / rowsum[row];
#pragma unroll
            for (int g = 0; g < 4; ++g)
                C[(long)row * N + colbase + g * 16] = acc[f][g][r] * inv;
        }
    }
}

// ---------------------------------------------------------------------------
extern "C" void kernel_launch(void* const* d_in, const int* in_sizes, int n_in,
                              void* d_out, int out_size, void* d_ws, size_t ws_size,
                              hipStream_t stream) {
    const float* in = (const float*)d_in[0];
    float* out = (float*)d_out;

    // ws layout: [rowsum 16KB] [xb 32MB bf16] [E 32MB bf16].
    // x8 (16MB fp8) lives in d_out's first 16MB -- dead until gemm_pv's
    // final write, which happens after gemm_sym has consumed x8.
    float* rowsum = (float*)d_ws;
    bf16* xb = (bf16*)((char*)d_ws + 16384);
    unsigned short* E = (unsigned short*)((char*)d_ws + 16384 + (size_t)N * N * sizeof(bf16));
    uint8_t* x8 = (uint8_t*)d_out;

    cvt_scale<<<(N * (long)N) / (256 * 8), 256, 0, stream>>>(
        in, (unsigned short*)xb, x8, rowsum);

    // E = exp(mask(x x^T)) via 136 triangular 256^2 fp8 8-phase tiles
    gemm_sym<<<136, 512, 0, stream>>>(x8, E, rowsum);
    // out = (E / rowsum) x^T  -- 256^2 8-phase, 256 blocks (1/CU)
    gemm_pv<<<256, 512, 0, stream>>>((const bf16*)E, xb, out, rowsum);
}

// Round 4
// 284.807 us; speedup vs baseline: 1.1640x; 1.1640x over previous
//
#include <hip/hip_runtime.h>
#include <hip/hip_bf16.h>
#include <stdint.h>

#define N 4096
#define BM 128     // sym tile (triangular 528-block grid)
#define SK 128     // fp8 K-tile
// gemm_pv 8-phase geometry:
#define PM 256
#define PN 256
#define PK 64

typedef __hip_bfloat16 bf16;
typedef __attribute__((ext_vector_type(8))) __bf16 bfrag;   // 8 bf16 (MFMA A/B operand)
typedef __attribute__((ext_vector_type(4))) float floatx4;  // MFMA C/D operand
typedef __attribute__((ext_vector_type(8))) int i32x8;      // 32 fp8 (f8f6f4 A/B operand)
typedef __attribute__((ext_vector_type(4))) int i32x4;

// ---------------------------------------------------------------------------
// async global -> LDS, 16B per lane (global_load_lds_dwordx4)
// ---------------------------------------------------------------------------
__device__ __forceinline__ void gld_lds16(const void* g, void* l) {
    __builtin_amdgcn_global_load_lds(
        (const __attribute__((address_space(1))) void*)g,
        (__attribute__((address_space(3))) void*)l, 16, 0, 0);
}

__device__ __forceinline__ unsigned short f2bf(float x) {
    __hip_bfloat16 h = __float2bfloat16(x);
    return *(unsigned short*)&h;
}

#define PV_BAR()   __builtin_amdgcn_s_barrier()
#define PV_LGKM0() asm volatile("s_waitcnt lgkmcnt(0)" ::: "memory")
#define PV_VM4()   asm volatile("s_waitcnt vmcnt(4)" ::: "memory")

// ---------------------------------------------------------------------------
// Kernel 1: xb = bf16(in * 1/64)  (scaled, for gemm_pv's B operand)
//           x8 = fp8_e4m3(in)     (UNSCALED -- the 1/4096 is applied exactly
//                                  via the MFMA e8m0 scale operands)
// blocks 0..15 also zero rowsum.
// ---------------------------------------------------------------------------
__global__ __launch_bounds__(256) void cvt_scale(const float* __restrict__ in,
                                                 unsigned short* __restrict__ xb,
                                                 uint8_t* __restrict__ x8,
                                                 float* __restrict__ rowsum) {
    if (blockIdx.x < 16) rowsum[blockIdx.x * 256 + threadIdx.x] = 0.f;
    const long i = ((long)blockIdx.x * 256 + threadIdx.x) * 8;
    float4 a = *(const float4*)(in + i);
    float4 b = *(const float4*)(in + i + 4);
    const float sc = 0.015625f;  // 1/64 = 1/sqrt(4096)
    float v[8] = {a.x, a.y, a.z, a.w, b.x, b.y, b.z, b.w};
    alignas(16) unsigned short r[8];
#pragma unroll
    for (int k = 0; k < 8; ++k) r[k] = f2bf(v[k] * sc);
    *(uint4*)(xb + i) = *(const uint4*)r;

    int p0 = __builtin_amdgcn_cvt_pk_fp8_f32(v[0], v[1], 0, false);
    p0     = __builtin_amdgcn_cvt_pk_fp8_f32(v[2], v[3], p0, true);
    int p1 = __builtin_amdgcn_cvt_pk_fp8_f32(v[4], v[5], 0, false);
    p1     = __builtin_amdgcn_cvt_pk_fp8_f32(v[6], v[7], p1, true);
    int2 pk; pk.x = p0; pk.y = p1;
    *(int2*)(x8 + i) = pk;
}

// ---------------------------------------------------------------------------
// Kernel 2 (gemm_sym): E = exp(mask(x x^T)), triangular 528-block grid of
// 128^2 tiles.  R9: REVERT to the m148/m97-proven skeleton (measured 1628 TF
// for MX-fp8 K=128 at exactly this geometry): 256 threads / 4 waves (2x2),
// 64x64 wave tile, single-buffered 32 KB LDS, 2-barrier K-loop.  R3's
// 256^2 8-phase failed: 53% grid fill (136 blocks) + 3.47M bank conflicts
// + MfmaUtil 21% per busy CU.  Here: 528 blocks (2.06 rounds, full fill),
// 3-4 blocks/CU resident -> cross-block overlap hides the syncthreads
// drains (m114).
// LDS swizzle: k-block c of row r stored at slot sigma(c)^(r&7), with
// sigma(c) = (c&1)*4 + (c>>1).  Fragment reads then hit slots q^l7 and
// (4+q)^l7 -- the EXACT byte pattern measured at 0 conflicts in R0-R5's pv
// (R3's (2q)^l7 pattern coincided with 3.47M conflicts).  Stager inverts:
// skb = sigma^-1((t&7)^(srow&7)), sigma^-1(x) = 2*(x&3) + (x>>2).
// ---------------------------------------------------------------------------
__global__ __launch_bounds__(256) void gemm_sym(const uint8_t* __restrict__ X8,
                                                unsigned short* __restrict__ E,
                                                float* __restrict__ rowsum) {
    __shared__ __align__(16) uint8_t smem[32768];
    uint8_t* As = smem;            // [128 rows][128 B] = 16 KB
    uint8_t* Bs = smem + 16384;    // 16 KB

    const int t    = threadIdx.x;
    const int lane = t & 63;
    const int wave = t >> 6;      // 0..3
    const int wm   = wave >> 1;   // 0..1  (64-row strip)
    const int wn   = wave & 1;    // 0..1  (64-col strip)
    const int l15  = lane & 15;
    const int l7   = lane & 7;
    const int q    = lane >> 4;

    // decode triangular block index: b = I*(I+1)/2 + J, J <= I  (32 rows)
    const int b = blockIdx.x;
    int I = (int)((sqrtf((float)(8 * b + 1)) - 1.0f) * 0.5f);
    if ((I + 1) * (I + 2) / 2 <= b) ++I;   // fp-safety fixups
    if (I * (I + 1) / 2 > b) --I;
    const int Jb = b - I * (I + 1) / 2;
    const int bm = I * BM;   // row block (>= col block)
    const int bn = Jb * BM;
    const bool diag = (I == Jb);

    floatx4 acc[4][4] = {};

    // staging: slot s=t covers row srow (32 rows/issue), slot t&7 holds
    // global k-block sigma^-1((t&7)^(srow&7))
    const int srow = t >> 3;                    // 0..31 (+32*i)
    const int x_   = (t & 7) ^ (srow & 7);
    const int skb  = ((x_ & 3) << 1) | (x_ >> 2);   // sigma^-1
    const uint8_t* Ag = X8 + (long)(bm + srow) * N + skb * 16;
    const uint8_t* Bg = X8 + (long)(bn + srow) * N + skb * 16;
    uint8_t* Asl = As + t * 16;
    uint8_t* Bsl = Bs + t * 16;

    for (int k0 = 0; k0 < N; k0 += SK) {
#pragma unroll
        for (int i = 0; i < 4; ++i) {
            // (srow + 32*i) & 7 == srow & 7: same swizzled k-block works
            gld_lds16(Ag + (long)i * 32 * N + k0, Asl + i * 4096);
            gld_lds16(Bg + (long)i * 32 * N + k0, Bsl + i * 4096);
        }
        __syncthreads();

        i32x8 af[4], bfr[4];
#pragma unroll
        for (int i = 0; i < 4; ++i) {
            const int row = wm * 64 + i * 16 + l15;   // row&7 == l7
            i32x4 lo = *(const i32x4*)&As[(row * 8 + (q ^ l7)) * 16];       // k-blk 2q
            i32x4 hi = *(const i32x4*)&As[(row * 8 + ((4 + q) ^ l7)) * 16]; // k-blk 2q+1
            af[i] = (i32x8){lo.x, lo.y, lo.z, lo.w, hi.x, hi.y, hi.z, hi.w};
        }
#pragma unroll
        for (int j = 0; j < 4; ++j) {
            const int row = wn * 64 + j * 16 + l15;
            i32x4 lo = *(const i32x4*)&Bs[(row * 8 + (q ^ l7)) * 16];
            i32x4 hi = *(const i32x4*)&Bs[(row * 8 + ((4 + q) ^ l7)) * 16];
            bfr[j] = (i32x8){lo.x, lo.y, lo.z, lo.w, hi.x, hi.y, hi.z, hi.w};
        }
#pragma unroll
        for (int i = 0; i < 4; ++i)
#pragma unroll
            for (int j = 0; j < 4; ++j)
                acc[i][j] = __builtin_amdgcn_mfma_scale_f32_16x16x128_f8f6f4(
                    af[i], bfr[j], acc[i][j],
                    0, 0,               // cbsz (A fp8 e4m3), blgp (B fp8)
                    0, 0x79797979,      // A scale: e8m0 121 = 2^-6
                    0, 0x79797979);     // B scale: 2^-6  (product: 1/4096)
        __syncthreads();
    }

    // ---- epilogue: C/D layout col=lane&15, row=(lane>>4)*4+reg ----
    const int col0 = bn + wn * 64 + l15;
    const int row0 = bm + wm * 64 + q * 4;

#pragma unroll
    for (int i = 0; i < 4; ++i) {
#pragma unroll
        for (int r = 0; r < 4; ++r) {
            const int row = row0 + i * 16 + r;
            float rs = 0.f;
#pragma unroll
            for (int j = 0; j < 4; ++j) {
                const int col = col0 + j * 16;
                // no max-subtraction: sims ~ +-0.3, exp safe; shift cancels.
                float e = (row == col) ? 0.f : __expf(acc[i][j][r]);
                acc[i][j][r] = e;
                rs += e;
                E[(long)row * N + col] = f2bf(e);
            }
#pragma unroll
            for (int off = 1; off < 16; off <<= 1) rs += __shfl_xor(rs, off);
            if (l15 == 0) atomicAdd(rowsum + row, rs);
        }
    }

    if (!diag) {
        // column sums -> row sums of the mirror tile
#pragma unroll
        for (int j = 0; j < 4; ++j) {
            float cs = 0.f;
#pragma unroll
            for (int i = 0; i < 4; ++i)
#pragma unroll
                for (int r = 0; r < 4; ++r) cs += acc[i][j][r];
            cs += __shfl_xor(cs, 16);
            cs += __shfl_xor(cs, 32);
            if (q == 0) atomicAdd(rowsum + bn + wn * 64 + j * 16 + l15, cs);
        }

        // per-wave 64x64 transpose through swizzled LDS (8 KB/wave, aliases
        // As/Bs; K-loop's trailing syncthreads has drained all LDS use)
        unsigned short* tb = (unsigned short*)smem + wave * 4096;
        __syncthreads();
#pragma unroll
        for (int i = 0; i < 4; ++i) {
            const int lr0 = i * 16 + q * 4;
            const int blk = lr0 >> 3;
            const int half = (lr0 >> 2) & 1;
#pragma unroll
            for (int j = 0; j < 4; ++j) {
                const int lc = j * 16 + l15;
                union { unsigned short u[4]; uint2 v2; } pk;
#pragma unroll
                for (int r = 0; r < 4; ++r) pk.u[r] = f2bf(acc[i][j][r]);
                *(uint2*)&tb[lc * 64 + 8 * (blk ^ (lc & 7)) + 4 * half] = pk.v2;
            }
        }
        __syncthreads();

        const int gr0 = lane >> 3;
        const int cb  = lane & 7;
#pragma unroll
        for (int p = 0; p < 8; ++p) {
            const int gr = p * 8 + gr0;
            uint4 v = *(const uint4*)&tb[gr * 64 + 8 * (cb ^ (gr & 7))];
            *(uint4*)&E[(long)(bn + wn * 64 + gr) * N + bm + wm * 64 + cb * 8] = v;
        }
    }
}

// ---------------------------------------------------------------------------
// Kernel 3 (gemm_pv): out = (E/rowsum) x^T.  256^2 8-phase schedule
// (T3+T4 counted-vmcnt + T5 setprio) -- unchanged from R6 (verified,
// 118 us / 1160 TF / MfmaUtil 49.5% / 0 conflicts).
// ---------------------------------------------------------------------------
#define PV_STAGE_A(buf, h, k0) do { \
    const bf16* s_ = Asrc + (h) * 128 * (long)N + (k0); \
    bf16* d_ = dstl + (buf) * 16384 + (h) * 8192; \
    gld_lds16(s_, d_); \
    gld_lds16(s_ + 64 * (long)N, d_ + 4096); } while (0)

#define PV_STAGE_B(buf, h, k0) do { \
    const bf16* s_ = Bsrc + (h) * 128 * (long)N + (k0); \
    bf16* d_ = dstl + 32768 + (buf) * 16384 + (h) * 8192; \
    gld_lds16(s_, d_); \
    gld_lds16(s_ + 64 * (long)N, d_ + 4096); } while (0)

#define PV_LDA(buf, mi) do { \
    const bf16* b_ = lds + (buf) * 16384; \
    _Pragma("unroll") for (int f_ = 0; f_ < 4; ++f_) { \
      const int r_ = wm * 128 + (mi) * 64 + f_ * 16 + l15; \
      ar[f_][0] = *(const bfrag*)&b_[(r_ * 8 + (q ^ l7)) * 8]; \
      ar[f_][1] = *(const bfrag*)&b_[(r_ * 8 + ((4 + q) ^ l7)) * 8]; } } while (0)

#define PV_LDB(buf, nj) do { \
    const bf16* b_ = lds + 32768 + (buf) * 16384; \
    _Pragma("unroll") for (int g_ = 0; g_ < 2; ++g_) { \
      const int r_ = wn * 64 + (nj) * 32 + g_ * 16 + l15; \
      br[nj][g_][0] = *(const bfrag*)&b_[(r_ * 8 + (q ^ l7)) * 8]; \
      br[nj][g_][1] = *(const bfrag*)&b_[(r_ * 8 + ((4 + q) ^ l7)) * 8]; } } while (0)

#define PV_MM(mi, nj) do { \
    __builtin_amdgcn_s_setprio(1); \
    _Pragma("unroll") for (int f_ = 0; f_ < 4; ++f_) \
    _Pragma("unroll") for (int g_ = 0; g_ < 2; ++g_) \
    _Pragma("unroll") for (int k_ = 0; k_ < 2; ++k_) \
      acc[(mi)*4+f_][(nj)*2+g_] = __builtin_amdgcn_mfma_f32_16x16x32_bf16( \
          ar[f_][k_], br[nj][g_][k_], acc[(mi)*4+f_][(nj)*2+g_], 0, 0, 0); \
    __builtin_amdgcn_s_setprio(0); } while (0)

__global__ __launch_bounds__(512, 2) void gemm_pv(const bf16* __restrict__ A,
                                                  const bf16* __restrict__ B,
                                                  float* __restrict__ C,
                                                  const float* __restrict__ rowsum) {
    __shared__ __align__(16) bf16 lds[4 * 16384];  // 128 KiB: A0 A1 B0 B1

    const int t    = threadIdx.x;
    const int lane = t & 63;
    const int wm   = (t >> 6) >> 2;  // 0..1 (128-row strip)
    const int wn   = (t >> 6) & 3;   // 0..3 (64-col strip)
    const int l15  = lane & 15;
    const int l7   = lane & 7;
    const int q    = lane >> 4;

    // bijective XCD swizzle (256 blocks % 8 XCDs == 0)
    const int swz = (blockIdx.x & 7) * 32 + (blockIdx.x >> 3);
    const int bm  = (swz >> 4) * PM;
    const int bn  = (swz & 15) * PN;

    const int srow = t >> 3;
    const int skb  = (t & 7) ^ (srow & 7);
    const bf16* Asrc = A + (long)(bm + srow) * N + skb * 8;
    const bf16* Bsrc = B + (long)(bn + srow) * N + skb * 8;
    bf16* dstl = lds + t * 8;

    floatx4 acc[8][4] = {};
    bfrag ar[4][2], br[2][2][2];

    // prologue: B(0),A(0) -> buf0; B(1) -> buf1.  A(1) staged in ph1/2.
    PV_STAGE_B(0, 0, 0); PV_STAGE_B(0, 1, 0);
    PV_STAGE_A(0, 0, 0); PV_STAGE_A(0, 1, 0);
    PV_STAGE_B(1, 0, PK); PV_STAGE_B(1, 1, PK);
    PV_VM4();
    PV_BAR();

    for (int i = 0; i < 32; ++i) {
        const int ka1 = ((2 * i + 1) * PK) & (N - 1);
        const int kb2 = ((2 * i + 2) * PK) & (N - 1);
        const int kb3 = ((2 * i + 3) * PK) & (N - 1);
        PV_LDA(0, 0); PV_LDB(0, 0); PV_STAGE_A(1, 0, ka1);
        PV_BAR(); PV_LGKM0();
        PV_MM(0, 0);
        PV_BAR();
        PV_LDB(0, 1); PV_STAGE_A(1, 1, ka1);
        PV_BAR(); PV_LGKM0();
        PV_MM(0, 1);
        PV_BAR();
        PV_LDA(0, 1); PV_STAGE_B(0, 0, kb2);
        PV_BAR(); PV_LGKM0();
        PV_MM(1, 1);
        PV_BAR();
        PV_STAGE_B(0, 1, kb2);
        PV_BAR();
        PV_MM(1, 0);
        PV_VM4(); PV_BAR();
        PV_LDA(1, 0); PV_LDB(1, 0); PV_STAGE_A(0, 0, kb2);
        PV_BAR(); PV_LGKM0();
        PV_MM(0, 0);
        PV_BAR();
        PV_LDB(1, 1); PV_STAGE_A(0, 1, kb2);
        PV_BAR(); PV_LGKM0();
        PV_MM(0, 1);
        PV_BAR();
        PV_LDA(1, 1); PV_STAGE_B(1, 0, kb3);
        PV_BAR(); PV_LGKM0();
        PV_MM(1, 1);
        PV_BAR();
        PV_STAGE_B(1, 1, kb3);
        PV_BAR();
        PV_MM(1, 0);
        PV_VM4(); PV_BAR();
    }

    // epilogue: C/D layout col=lane&15, row=q*4+reg; fuse 1/rowsum
    const int rowbase = bm + wm * 128 + q * 4;
    const int colbase = bn + wn * 64 + l15;
#pragma unroll
    for (int f = 0; f < 8; ++f) {
#pragma unroll
        for (int r = 0; r < 4; ++r) {
            const int row = rowbase + f * 16 + r;
            const float inv = 1.0f / rowsum[row];
#pragma unroll
            for (int g = 0; g < 4; ++g)
                C[(long)row * N + colbase + g * 16] = acc[f][g][r] * inv;
        }
    }
}

// ---------------------------------------------------------------------------
extern "C" void kernel_launch(void* const* d_in, const int* in_sizes, int n_in,
                              void* d_out, int out_size, void* d_ws, size_t ws_size,
                              hipStream_t stream) {
    const float* in = (const float*)d_in[0];
    float* out = (float*)d_out;

    // ws layout: [rowsum 16KB] [xb 32MB bf16] [E 32MB bf16].
    // x8 (16MB fp8) lives in d_out's first 16MB -- dead until gemm_pv's
    // final write, which happens after gemm_sym has consumed x8.
    float* rowsum = (float*)d_ws;
    bf16* xb = (bf16*)((char*)d_ws + 16384);
    unsigned short* E = (unsigned short*)((char*)d_ws + 16384 + (size_t)N * N * sizeof(bf16));
    uint8_t* x8 = (uint8_t*)d_out;

    cvt_scale<<<(N * (long)N) / (256 * 8), 256, 0, stream>>>(
        in, (unsigned short*)xb, x8, rowsum);

    // E = exp(mask(x x^T)) via 528 triangular 128^2 fp8 tiles (m148 skeleton)
    gemm_sym<<<528, 256, 0, stream>>>(x8, E, rowsum);
    // out = (E / rowsum) x^T  -- 256^2 8-phase, 256 blocks (1/CU)
    gemm_pv<<<256, 512, 0, stream>>>((const bf16*)E, xb, out, rowsum);
}

// Round 7
// 274.973 us; speedup vs baseline: 1.2057x; 1.0358x over previous
//
#include <hip/hip_runtime.h>
#include <hip/hip_bf16.h>
#include <stdint.h>

#define N 4096
#define BM 128     // sym tile (triangular 528-block grid)
#define SK 128     // fp8 K-tile
// gemm_pv 8-phase geometry:
#define PM 256
#define PN 256
#define PK 64

typedef __hip_bfloat16 bf16;
typedef __attribute__((ext_vector_type(8))) __bf16 bfrag;   // 8 bf16 (MFMA A/B operand)
typedef __attribute__((ext_vector_type(4))) float floatx4;  // MFMA C/D operand
typedef __attribute__((ext_vector_type(8))) int i32x8;      // 32 fp8 (f8f6f4 A/B operand)
typedef __attribute__((ext_vector_type(4))) int i32x4;

// ---------------------------------------------------------------------------
// async global -> LDS, 16B per lane (global_load_lds_dwordx4)
// ---------------------------------------------------------------------------
__device__ __forceinline__ void gld_lds16(const void* g, void* l) {
    __builtin_amdgcn_global_load_lds(
        (const __attribute__((address_space(1))) void*)g,
        (__attribute__((address_space(3))) void*)l, 16, 0, 0);
}

__device__ __forceinline__ unsigned short f2bf(float x) {
    __hip_bfloat16 h = __float2bfloat16(x);
    return *(unsigned short*)&h;
}

#define PV_BAR()   __builtin_amdgcn_s_barrier()
#define PV_LGKM0() asm volatile("s_waitcnt lgkmcnt(0)" ::: "memory")
#define PV_VM4()   asm volatile("s_waitcnt vmcnt(4)" ::: "memory")

// ---------------------------------------------------------------------------
// Kernel 1: xb = bf16(in * 1/64)  (scaled, for gemm_pv's B operand)
//           x8 = fp8_e4m3(in)     (UNSCALED -- the 1/4096 is applied exactly
//                                  via the MFMA e8m0 scale operands)
// blocks 0..15 also zero rowsum.
// ---------------------------------------------------------------------------
__global__ __launch_bounds__(256) void cvt_scale(const float* __restrict__ in,
                                                 unsigned short* __restrict__ xb,
                                                 uint8_t* __restrict__ x8,
                                                 float* __restrict__ rowsum) {
    if (blockIdx.x < 16) rowsum[blockIdx.x * 256 + threadIdx.x] = 0.f;
    const long i = ((long)blockIdx.x * 256 + threadIdx.x) * 8;
    float4 a = *(const float4*)(in + i);
    float4 b = *(const float4*)(in + i + 4);
    const float sc = 0.015625f;  // 1/64 = 1/sqrt(4096)
    float v[8] = {a.x, a.y, a.z, a.w, b.x, b.y, b.z, b.w};
    alignas(16) unsigned short r[8];
#pragma unroll
    for (int k = 0; k < 8; ++k) r[k] = f2bf(v[k] * sc);
    *(uint4*)(xb + i) = *(const uint4*)r;

    int p0 = __builtin_amdgcn_cvt_pk_fp8_f32(v[0], v[1], 0, false);
    p0     = __builtin_amdgcn_cvt_pk_fp8_f32(v[2], v[3], p0, true);
    int p1 = __builtin_amdgcn_cvt_pk_fp8_f32(v[4], v[5], 0, false);
    p1     = __builtin_amdgcn_cvt_pk_fp8_f32(v[6], v[7], p1, true);
    int2 pk; pk.x = p0; pk.y = p1;
    *(int2*)(x8 + i) = pk;
}

// ---------------------------------------------------------------------------
// Kernel 2 (gemm_sym): E = exp(mask(x x^T)), triangular 528-block grid of
// 128^2 tiles, 256 threads / 4 waves (2x2), 64x64 wave tile, fp8 K=128 via
// mfma_scale_f32_16x16x128_f8f6f4 (e8m0 2^-6 scales -> exact 1/4096).
// R10 (vs R4, which tied R1's original at ~86 us = 18% MFMA util):
//  (1) T3 minimum-2-phase prefetch (m230-V0 recipe): double-buffered 64 KB
//      LDS; stage tile t+1 FIRST, then ds_read+MFMA tile t, then ONE
//      __syncthreads per tile.  R4 staged-then-drained (vmcnt(0) inside
//      syncthreads) with only ~2 blocks/CU -> full L2/HBM latency exposed
//      every iteration.  Now the prefetch has the whole ~550-cyc compute
//      phase to land.  Last prefetch guarded so no in-flight loads race the
//      epilogue's LDS-transpose reuse.
//  (2) bijective XCD-chunk swizzle (528 = 8x66): XCD x owns triangle blocks
//      [66x, 66x+65] -- a contiguous row band -> A/B panel L2 locality.
// LDS swizzle unchanged (verified-pattern): k-block c of row r stored at
// slot sigma(c)^(r&7), sigma(c) = (c&1)*4 + (c>>1); fragment reads hit
// slots q^l7 and (4+q)^l7 -- the exact byte pattern measured at 0 conflicts
// in pv for five rounds.  Stager: skb = sigma^-1((t&7)^(srow&7)).
// ---------------------------------------------------------------------------
__global__ __launch_bounds__(256) void gemm_sym(const uint8_t* __restrict__ X8,
                                                unsigned short* __restrict__ E,
                                                float* __restrict__ rowsum) {
    __shared__ __align__(16) uint8_t smem[65536];  // 2 x (A 16KB + B 16KB)

    const int t    = threadIdx.x;
    const int lane = t & 63;
    const int wave = t >> 6;      // 0..3
    const int wm   = wave >> 1;   // 0..1  (64-row strip)
    const int wn   = wave & 1;    // 0..1  (64-col strip)
    const int l15  = lane & 15;
    const int l7   = lane & 7;
    const int q    = lane >> 4;

    // XCD-chunk swizzle: HW round-robins blockIdx across 8 XCDs; give XCD x
    // the contiguous triangle range [66x, 66x+65].
    const int b0 = blockIdx.x;
    const int b  = (b0 & 7) * 66 + (b0 >> 3);
    // decode triangular block index: b = I*(I+1)/2 + J, J <= I  (32 rows)
    int I = (int)((sqrtf((float)(8 * b + 1)) - 1.0f) * 0.5f);
    if ((I + 1) * (I + 2) / 2 <= b) ++I;   // fp-safety fixups
    if (I * (I + 1) / 2 > b) --I;
    const int Jb = b - I * (I + 1) / 2;
    const int bm = I * BM;   // row block (>= col block)
    const int bn = Jb * BM;
    const bool diag = (I == Jb);

    floatx4 acc[4][4] = {};

    // staging: slot s=t covers row srow (32 rows/issue), slot t&7 holds
    // global k-block sigma^-1((t&7)^(srow&7))
    const int srow = t >> 3;                    // 0..31 (+32*i)
    const int x_   = (t & 7) ^ (srow & 7);
    const int skb  = ((x_ & 3) << 1) | (x_ >> 2);   // sigma^-1
    const uint8_t* Ag = X8 + (long)(bm + srow) * N + skb * 16;
    const uint8_t* Bg = X8 + (long)(bn + srow) * N + skb * 16;

    // prologue: stage tile 0 into buf 0
#pragma unroll
    for (int i = 0; i < 4; ++i) {
        gld_lds16(Ag + (long)i * 32 * N, smem + t * 16 + i * 4096);
        gld_lds16(Bg + (long)i * 32 * N, smem + 16384 + t * 16 + i * 4096);
    }
    __syncthreads();

    int cur = 0;
    for (int k0 = 0; k0 < N; k0 += SK) {
        // prefetch tile t+1 into buf cur^1 (issued BEFORE compute; lands
        // during the reads+MFMA below; drained by this iter's syncthreads)
        if (k0 + SK < N) {
            uint8_t* An = smem + (cur ^ 1) * 32768 + t * 16;
#pragma unroll
            for (int i = 0; i < 4; ++i) {
                gld_lds16(Ag + (long)i * 32 * N + k0 + SK, An + i * 4096);
                gld_lds16(Bg + (long)i * 32 * N + k0 + SK, An + 16384 + i * 4096);
            }
        }

        const uint8_t* As = smem + cur * 32768;
        const uint8_t* Bs = As + 16384;
        i32x8 af[4], bfr[4];
#pragma unroll
        for (int i = 0; i < 4; ++i) {
            const int row = wm * 64 + i * 16 + l15;   // row&7 == l7
            i32x4 lo = *(const i32x4*)&As[(row * 8 + (q ^ l7)) * 16];       // k-blk 2q
            i32x4 hi = *(const i32x4*)&As[(row * 8 + ((4 + q) ^ l7)) * 16]; // k-blk 2q+1
            af[i] = (i32x8){lo.x, lo.y, lo.z, lo.w, hi.x, hi.y, hi.z, hi.w};
        }
#pragma unroll
        for (int j = 0; j < 4; ++j) {
            const int row = wn * 64 + j * 16 + l15;
            i32x4 lo = *(const i32x4*)&Bs[(row * 8 + (q ^ l7)) * 16];
            i32x4 hi = *(const i32x4*)&Bs[(row * 8 + ((4 + q) ^ l7)) * 16];
            bfr[j] = (i32x8){lo.x, lo.y, lo.z, lo.w, hi.x, hi.y, hi.z, hi.w};
        }
#pragma unroll
        for (int i = 0; i < 4; ++i)
#pragma unroll
            for (int j = 0; j < 4; ++j)
                acc[i][j] = __builtin_amdgcn_mfma_scale_f32_16x16x128_f8f6f4(
                    af[i], bfr[j], acc[i][j],
                    0, 0,               // cbsz (A fp8 e4m3), blgp (B fp8)
                    0, 0x79797979,      // A scale: e8m0 121 = 2^-6
                    0, 0x79797979);     // B scale: 2^-6  (product: 1/4096)
        __syncthreads();  // drains own-wave vmcnt (prefetch landed) + joins
        cur ^= 1;
    }

    // ---- epilogue: C/D layout col=lane&15, row=(lane>>4)*4+reg ----
    const int col0 = bn + wn * 64 + l15;
    const int row0 = bm + wm * 64 + q * 4;

#pragma unroll
    for (int i = 0; i < 4; ++i) {
#pragma unroll
        for (int r = 0; r < 4; ++r) {
            const int row = row0 + i * 16 + r;
            float rs = 0.f;
#pragma unroll
            for (int j = 0; j < 4; ++j) {
                const int col = col0 + j * 16;
                // no max-subtraction: sims ~ +-0.3, exp safe; shift cancels.
                float e = (row == col) ? 0.f : __expf(acc[i][j][r]);
                acc[i][j][r] = e;
                rs += e;
                E[(long)row * N + col] = f2bf(e);
            }
#pragma unroll
            for (int off = 1; off < 16; off <<= 1) rs += __shfl_xor(rs, off);
            if (l15 == 0) atomicAdd(rowsum + row, rs);
        }
    }

    if (!diag) {
        // column sums -> row sums of the mirror tile
#pragma unroll
        for (int j = 0; j < 4; ++j) {
            float cs = 0.f;
#pragma unroll
            for (int i = 0; i < 4; ++i)
#pragma unroll
                for (int r = 0; r < 4; ++r) cs += acc[i][j][r];
            cs += __shfl_xor(cs, 16);
            cs += __shfl_xor(cs, 32);
            if (q == 0) atomicAdd(rowsum + bn + wn * 64 + j * 16 + l15, cs);
        }

        // per-wave 64x64 transpose through swizzled LDS (8 KB/wave; the
        // K-loop's final syncthreads drained all staging, and the guarded
        // last prefetch means no loads are still in flight)
        unsigned short* tb = (unsigned short*)smem + wave * 4096;
        __syncthreads();
#pragma unroll
        for (int i = 0; i < 4; ++i) {
            const int lr0 = i * 16 + q * 4;
            const int blk = lr0 >> 3;
            const int half = (lr0 >> 2) & 1;
#pragma unroll
            for (int j = 0; j < 4; ++j) {
                const int lc = j * 16 + l15;
                union { unsigned short u[4]; uint2 v2; } pk;
#pragma unroll
                for (int r = 0; r < 4; ++r) pk.u[r] = f2bf(acc[i][j][r]);
                *(uint2*)&tb[lc * 64 + 8 * (blk ^ (lc & 7)) + 4 * half] = pk.v2;
            }
        }
        __syncthreads();

        const int gr0 = lane >> 3;
        const int cb  = lane & 7;
#pragma unroll
        for (int p = 0; p < 8; ++p) {
            const int gr = p * 8 + gr0;
            uint4 v = *(const uint4*)&tb[gr * 64 + 8 * (cb ^ (gr & 7))];
            *(uint4*)&E[(long)(bn + wn * 64 + gr) * N + bm + wm * 64 + cb * 8] = v;
        }
    }
}

// ---------------------------------------------------------------------------
// Kernel 3 (gemm_pv): out = (E/rowsum) x^T.  256^2 8-phase schedule
// (T3+T4 counted-vmcnt + T5 setprio) -- unchanged from R6 (verified,
// ~118-120 us / 1160 TF / MfmaUtil 48-49% / 0 conflicts).
// ---------------------------------------------------------------------------
#define PV_STAGE_A(buf, h, k0) do { \
    const bf16* s_ = Asrc + (h) * 128 * (long)N + (k0); \
    bf16* d_ = dstl + (buf) * 16384 + (h) * 8192; \
    gld_lds16(s_, d_); \
    gld_lds16(s_ + 64 * (long)N, d_ + 4096); } while (0)

#define PV_STAGE_B(buf, h, k0) do { \
    const bf16* s_ = Bsrc + (h) * 128 * (long)N + (k0); \
    bf16* d_ = dstl + 32768 + (buf) * 16384 + (h) * 8192; \
    gld_lds16(s_, d_); \
    gld_lds16(s_ + 64 * (long)N, d_ + 4096); } while (0)

#define PV_LDA(buf, mi) do { \
    const bf16* b_ = lds + (buf) * 16384; \
    _Pragma("unroll") for (int f_ = 0; f_ < 4; ++f_) { \
      const int r_ = wm * 128 + (mi) * 64 + f_ * 16 + l15; \
      ar[f_][0] = *(const bfrag*)&b_[(r_ * 8 + (q ^ l7)) * 8]; \
      ar[f_][1] = *(const bfrag*)&b_[(r_ * 8 + ((4 + q) ^ l7)) * 8]; } } while (0)

#define PV_LDB(buf, nj) do { \
    const bf16* b_ = lds + 32768 + (buf) * 16384; \
    _Pragma("unroll") for (int g_ = 0; g_ < 2; ++g_) { \
      const int r_ = wn * 64 + (nj) * 32 + g_ * 16 + l15; \
      br[nj][g_][0] = *(const bfrag*)&b_[(r_ * 8 + (q ^ l7)) * 8]; \
      br[nj][g_][1] = *(const bfrag*)&b_[(r_ * 8 + ((4 + q) ^ l7)) * 8]; } } while (0)

#define PV_MM(mi, nj) do { \
    __builtin_amdgcn_s_setprio(1); \
    _Pragma("unroll") for (int f_ = 0; f_ < 4; ++f_) \
    _Pragma("unroll") for (int g_ = 0; g_ < 2; ++g_) \
    _Pragma("unroll") for (int k_ = 0; k_ < 2; ++k_) \
      acc[(mi)*4+f_][(nj)*2+g_] = __builtin_amdgcn_mfma_f32_16x16x32_bf16( \
          ar[f_][k_], br[nj][g_][k_], acc[(mi)*4+f_][(nj)*2+g_], 0, 0, 0); \
    __builtin_amdgcn_s_setprio(0); } while (0)

__global__ __launch_bounds__(512, 2) void gemm_pv(const bf16* __restrict__ A,
                                                  const bf16* __restrict__ B,
                                                  float* __restrict__ C,
                                                  const float* __restrict__ rowsum) {
    __shared__ __align__(16) bf16 lds[4 * 16384];  // 128 KiB: A0 A1 B0 B1

    const int t    = threadIdx.x;
    const int lane = t & 63;
    const int wm   = (t >> 6) >> 2;  // 0..1 (128-row strip)
    const int wn   = (t >> 6) & 3;   // 0..3 (64-col strip)
    const int l15  = lane & 15;
    const int l7   = lane & 7;
    const int q    = lane >> 4;

    // bijective XCD swizzle (256 blocks % 8 XCDs == 0)
    const int swz = (blockIdx.x & 7) * 32 + (blockIdx.x >> 3);
    const int bm  = (swz >> 4) * PM;
    const int bn  = (swz & 15) * PN;

    const int srow = t >> 3;
    const int skb  = (t & 7) ^ (srow & 7);
    const bf16* Asrc = A + (long)(bm + srow) * N + skb * 8;
    const bf16* Bsrc = B + (long)(bn + srow) * N + skb * 8;
    bf16* dstl = lds + t * 8;

    floatx4 acc[8][4] = {};
    bfrag ar[4][2], br[2][2][2];

    // prologue: B(0),A(0) -> buf0; B(1) -> buf1.  A(1) staged in ph1/2.
    PV_STAGE_B(0, 0, 0); PV_STAGE_B(0, 1, 0);
    PV_STAGE_A(0, 0, 0); PV_STAGE_A(0, 1, 0);
    PV_STAGE_B(1, 0, PK); PV_STAGE_B(1, 1, PK);
    PV_VM4();
    PV_BAR();

    for (int i = 0; i < 32; ++i) {
        const int ka1 = ((2 * i + 1) * PK) & (N - 1);
        const int kb2 = ((2 * i + 2) * PK) & (N - 1);
        const int kb3 = ((2 * i + 3) * PK) & (N - 1);
        PV_LDA(0, 0); PV_LDB(0, 0); PV_STAGE_A(1, 0, ka1);
        PV_BAR(); PV_LGKM0();
        PV_MM(0, 0);
        PV_BAR();
        PV_LDB(0, 1); PV_STAGE_A(1, 1, ka1);
        PV_BAR(); PV_LGKM0();
        PV_MM(0, 1);
        PV_BAR();
        PV_LDA(0, 1); PV_STAGE_B(0, 0, kb2);
        PV_BAR(); PV_LGKM0();
        PV_MM(1, 1);
        PV_BAR();
        PV_STAGE_B(0, 1, kb2);
        PV_BAR();
        PV_MM(1, 0);
        PV_VM4(); PV_BAR();
        PV_LDA(1, 0); PV_LDB(1, 0); PV_STAGE_A(0, 0, kb2);
        PV_BAR(); PV_LGKM0();
        PV_MM(0, 0);
        PV_BAR();
        PV_LDB(1, 1); PV_STAGE_A(0, 1, kb2);
        PV_BAR(); PV_LGKM0();
        PV_MM(0, 1);
        PV_BAR();
        PV_LDA(1, 1); PV_STAGE_B(1, 0, kb3);
        PV_BAR(); PV_LGKM0();
        PV_MM(1, 1);
        PV_BAR();
        PV_STAGE_B(1, 1, kb3);
        PV_BAR();
        PV_MM(1, 0);
        PV_VM4(); PV_BAR();
    }

    // epilogue: C/D layout col=lane&15, row=q*4+reg; fuse 1/rowsum
    const int rowbase = bm + wm * 128 + q * 4;
    const int colbase = bn + wn * 64 + l15;
#pragma unroll
    for (int f = 0; f < 8; ++f) {
#pragma unroll
        for (int r = 0; r < 4; ++r) {
            const int row = rowbase + f * 16 + r;
            const float inv = 1.0f / rowsum[row];
#pragma unroll
            for (int g = 0; g < 4; ++g)
                C[(long)row * N + colbase + g * 16] = acc[f][g][r] * inv;
        }
    }
}

// ---------------------------------------------------------------------------
extern "C" void kernel_launch(void* const* d_in, const int* in_sizes, int n_in,
                              void* d_out, int out_size, void* d_ws, size_t ws_size,
                              hipStream_t stream) {
    const float* in = (const float*)d_in[0];
    float* out = (float*)d_out;

    // ws layout: [rowsum 16KB] [xb 32MB bf16] [E 32MB bf16].
    // x8 (16MB fp8) lives in d_out's first 16MB -- dead until gemm_pv's
    // final write, which happens after gemm_sym has consumed x8.
    float* rowsum = (float*)d_ws;
    bf16* xb = (bf16*)((char*)d_ws + 16384);
    unsigned short* E = (unsigned short*)((char*)d_ws + 16384 + (size_t)N * N * sizeof(bf16));
    uint8_t* x8 = (uint8_t*)d_out;

    cvt_scale<<<(N * (long)N) / (256 * 8), 256, 0, stream>>>(
        in, (unsigned short*)xb, x8, rowsum);

    // E = exp(mask(x x^T)) via 528 triangular 128^2 fp8 tiles
    // (2-phase prefetch dbuf + XCD-chunk swizzle)
    gemm_sym<<<528, 256, 0, stream>>>(x8, E, rowsum);
    // out = (E / rowsum) x^T  -- 256^2 8-phase, 256 blocks (1/CU)
    gemm_pv<<<256, 512, 0, stream>>>((const bf16*)E, xb, out, rowsum);
}